// Round 11
// baseline (84.977 us; speedup 1.0000x reference)
//
#include <hip/hip_runtime.h>

#define B_SZ 8192
#define SP 8256  // padded row stride (floats): breaks 32KB power-of-2 L2-channel aliasing

// ---------------- transpose x [8192,256] -> xT [256][SP] ----------------
__global__ __launch_bounds__(256) void ndt_transpose(const float* __restrict__ x,
                                                     float* __restrict__ xT) {
  __shared__ float tile[32][33];
  int f0 = blockIdx.x * 32;
  int b0 = blockIdx.y * 32;
  int tx = threadIdx.x, ty = threadIdx.y;
#pragma unroll
  for (int k = 0; k < 32; k += 8)
    tile[ty + k][tx] = x[(size_t)(b0 + ty + k) * 256 + f0 + tx];
  __syncthreads();
#pragma unroll
  for (int k = 0; k < 32; k += 8)
    xT[(size_t)(f0 + ty + k) * SP + b0 + tx] = tile[tx][ty + k];
}

// ---------------- masks (exact 1.5-entmax via bisection) + fused params ----------------
struct MaskArgs {
  const float* fm[6];
  const float* cp[6];
  const float* lr[6];
  float* out_masks;  // d_out base
  float4* prm;       // fused params {c10, ml0/8, ml1/8, 0}
  float* cstf;       // flat per-output 0.5*sum(ml): level d at 2*cstOff[d]
};

__device__ __forceinline__ float wave_max(float v) {
#pragma unroll
  for (int o = 32; o > 0; o >>= 1) v = fmaxf(v, __shfl_xor(v, o));
  return v;
}
__device__ __forceinline__ float wave_sum(float v) {
#pragma unroll
  for (int o = 32; o > 0; o >>= 1) v += __shfl_xor(v, o);
  return v;
}

__global__ __launch_bounds__(64) void ndt_masks(MaskArgs a) {
  const int maskOff[6] = {524288, 524544, 525060, 526100, 528212, 532564};
  const int prmOff[6]  = {0, 256, 772, 1812, 3924, 8276};
  const int cstOff[6]  = {0, 1, 3, 7, 15, 31};
  int bid = blockIdx.x, lane = threadIdx.x;
  int d = 0, s = bid, n = 1;
  while (s >= n) { s -= n; n <<= 1; ++d; }   // level d, stump s, n = 2^d
  int Fd = 256 + ((d > 0) ? n : 0);

  const float* fm = a.fm[d] + (size_t)s * Fd;
  float y[5];
#pragma unroll
  for (int j = 0; j < 5; ++j) {
    int f = lane + 64 * j;
    y[j] = (f < Fd) ? fm[f] * 0.5f : -3.0e38f;
  }
  float m = fmaxf(fmaxf(fmaxf(y[0], y[1]), fmaxf(y[2], y[3])), y[4]);
  m = wave_max(m);
#pragma unroll
  for (int j = 0; j < 5; ++j) y[j] -= m;

  // solve sum clip(y - tau, 0)^2 = 1 ; tau in [-1, 0], strictly decreasing in tau
  float lo = -1.f, hi = 0.f;
  for (int it = 0; it < 24; ++it) {
    float tau = 0.5f * (lo + hi);
    float ss = 0.f;
#pragma unroll
    for (int j = 0; j < 5; ++j) {
      float v = fmaxf(y[j] - tau, 0.f);
      ss = __builtin_fmaf(v, v, ss);
    }
    ss = wave_sum(ss);
    if (ss >= 1.f) lo = tau; else hi = tau;
  }
  float tau = 0.5f * (lo + hi);

  float* mo = a.out_masks + maskOff[d] + (size_t)s * Fd;
  const float* cp = a.cp[d] + (size_t)s * Fd * 2;
  const float* lr = a.lr[d] + (size_t)s * Fd * 2;
  float4* pr = a.prm + prmOff[d] + (size_t)s * Fd;
  float sum0 = 0.f, sum1 = 0.f;
#pragma unroll
  for (int j = 0; j < 5; ++j) {
    int f = lane + 64 * j;
    if (f < Fd) {
      float v = fmaxf(y[j] - tau, 0.f);
      float mk = v * v;
      mo[f] = mk;
      float c0 = cp[2 * f], c1 = cp[2 * f + 1];
      float ml0 = lr[2 * f] * mk, ml1 = lr[2 * f + 1] * mk;
      sum0 += ml0;
      sum1 += ml1;
      // store ml/8: entpair returns e' = 8e, so e'*(ml/8) = e*ml
      pr[f] = make_float4(c1 - c0, ml0 * 0.125f, ml1 * 0.125f, 0.f);
    }
  }
  sum0 = wave_sum(sum0);
  sum1 = wave_sum(sum1);
  if (lane == 0) {
    a.cstf[2 * (cstOff[d] + s)] = 0.5f * sum0;
    a.cstf[2 * (cstOff[d] + s) + 1] = 0.5f * sum1;
  }
}

// 2-elem entmax15 closed form (scaled): t = c10 - x; tc = clamp(t,-2,2);
// e' = tc*sqrt(8 - tc^2) = 8*e;  p0 = 0.5 + e'/8, p1 = 0.5 - e'/8.
// The 1/8 is folded into the ml params at build time.
__device__ __forceinline__ float entpair(float c10, float xv) {
  float t = c10 - xv;
  float tc = __builtin_amdgcn_fmed3f(t, -2.f, 2.f);
  float u = __builtin_fmaf(tc, -tc, 8.0f);
  return tc * __builtin_amdgcn_sqrtf(u);
}

// ---------------- levels 0-2 fused: 32-row blocks, 8 groups x 32 lanes ----------------
// Writes out2 TRANSPOSED with padded stride: out2T[o][row], o in [0,8).
__global__ __launch_bounds__(256) void ndt_l012(const float* __restrict__ x,
                                                const float4* __restrict__ prm,
                                                const float* __restrict__ cstf,
                                                float* __restrict__ out2T) {
  __shared__ float xls[256 * 32];
  __shared__ float4 pl[1812];
  __shared__ float pbuf[8][2][32];
  int tid = threadIdx.x;
  int r = tid & 31, c = tid >> 5;
  int b0 = blockIdx.x * 32;
  for (int i = tid; i < 1812; i += 256) pl[i] = prm[i];
  {
    const float4* xp = (const float4*)(x + (size_t)(b0 + r) * 256 + c * 32);
#pragma unroll
    for (int j = 0; j < 8; ++j) {
      float4 g = xp[j];
      int f = c * 32 + 4 * j;
      xls[(f + 0) * 32 + (r ^ ((4 * j + 0) & 31))] = g.x;
      xls[(f + 1) * 32 + (r ^ ((4 * j + 1) & 31))] = g.y;
      xls[(f + 2) * 32 + (r ^ ((4 * j + 2) & 31))] = g.z;
      xls[(f + 3) * 32 + (r ^ ((4 * j + 3) & 31))] = g.w;
    }
  }
  __syncthreads();
  // ---- L0: group c -> features [c*32, c*32+32)
  float a0 = 0.f, a1 = 0.f;
#pragma unroll
  for (int j = 0; j < 32; ++j) {
    int f = c * 32 + j;
    float xv = xls[f * 32 + (r ^ j)];
    float4 p = pl[f];
    float e = entpair(p.x, xv);
    a0 = __builtin_fmaf(e, p.y, a0);
    a1 = __builtin_fmaf(-e, p.z, a1);
  }
  pbuf[c][0][r] = a0;
  pbuf[c][1][r] = a1;
  __syncthreads();
  float xe1[2];
#pragma unroll
  for (int o = 0; o < 2; ++o) {
    float v = cstf[o];
#pragma unroll
    for (int k = 0; k < 8; ++k) v += pbuf[k][o][r];
    xe1[o] = v;
  }
  __syncthreads();
  // ---- L1: stump c>>2, feature slice (c&3)*64; extras on slice 0
  {
    int s = c >> 2, fs = c & 3;
    const float4* ps = &pl[256 + s * 258];
    a0 = 0.f;
    a1 = 0.f;
#pragma unroll
    for (int j = 0; j < 64; ++j) {
      int f = fs * 64 + j;
      float xv = xls[f * 32 + (r ^ (f & 31))];
      float4 p = ps[f];
      float e = entpair(p.x, xv);
      a0 = __builtin_fmaf(e, p.y, a0);
      a1 = __builtin_fmaf(-e, p.z, a1);
    }
    if (fs == 0) {
#pragma unroll
      for (int o = 0; o < 2; ++o) {
        float4 p = ps[256 + o];
        float e = entpair(p.x, xe1[o]);
        a0 = __builtin_fmaf(e, p.y, a0);
        a1 = __builtin_fmaf(-e, p.z, a1);
      }
    }
    pbuf[c][0][r] = a0;
    pbuf[c][1][r] = a1;
  }
  __syncthreads();
  float xe2[4];
#pragma unroll
  for (int s = 0; s < 2; ++s)
#pragma unroll
    for (int o = 0; o < 2; ++o) {
      float v = cstf[2 + 2 * s + o];
#pragma unroll
      for (int k = 0; k < 4; ++k) v += pbuf[4 * s + k][o][r];
      xe2[2 * s + o] = v;
    }
  __syncthreads();
  // ---- L2: stump c>>1, feature slice (c&1)*128; extras on slice 0
  {
    int s = c >> 1, fs = c & 1;
    const float4* ps = &pl[772 + s * 260];
    a0 = 0.f;
    a1 = 0.f;
#pragma unroll
    for (int j = 0; j < 128; ++j) {
      int f = fs * 128 + j;
      float xv = xls[f * 32 + (r ^ (f & 31))];
      float4 p = ps[f];
      float e = entpair(p.x, xv);
      a0 = __builtin_fmaf(e, p.y, a0);
      a1 = __builtin_fmaf(-e, p.z, a1);
    }
    if (fs == 0) {
#pragma unroll
      for (int o = 0; o < 4; ++o) {
        float4 p = ps[256 + o];
        float e = entpair(p.x, xe2[o]);
        a0 = __builtin_fmaf(e, p.y, a0);
        a1 = __builtin_fmaf(-e, p.z, a1);
      }
    }
    pbuf[c][0][r] = a0;
    pbuf[c][1][r] = a1;
  }
  __syncthreads();
  // ---- reduce L2 -> out2T[4c+i][b0+r]
  if (c < 2) {
#pragma unroll
    for (int i = 0; i < 4; ++i) {
      int s = 2 * c + (i >> 1), o = i & 1;
      float v = cstf[6 + 2 * s + o];
#pragma unroll
      for (int k = 0; k < 2; ++k) v += pbuf[2 * s + k][o][r];
      out2T[(size_t)(4 * c + i) * SP + b0 + r] = v;
    }
  }
}

// ---------------- big levels (3,4,5): feature-major, NSW stumps/block ----------
// Block = 512 thr: group fh (0/1) of 256 threads handles features [fh*128,(fh+1)*128);
// group 1 also does the EX prev-level features. One x load feeds NSW stumps (regs),
// cutting L2 read volume by NSW. Partials combine via LDS. Params in LDS broadcast.
// Grid (32 colblks, n/NSW).
template <int EX, int NSW, bool FINAL>
__global__ __launch_bounds__(512, 4) void ndt_bigT(const float* __restrict__ xT,
                                                   const float* __restrict__ prevT,
                                                   const float4* __restrict__ prmL,
                                                   const float* __restrict__ cstL,
                                                   float* __restrict__ outp) {
  constexpr int FD = 256 + EX;
  __shared__ float4 pl[NSW * FD];
  __shared__ float2 pb[NSW][256];
  int tid = threadIdx.x;
  int lcol = tid & 255, fh = tid >> 8;
  int s0 = blockIdx.y * NSW;
  for (int i = tid; i < NSW * FD; i += 512) pl[i] = prmL[(size_t)s0 * FD + i];
  __syncthreads();

  int col = blockIdx.x * 256 + lcol;
  float a0[NSW], a1[NSW];
#pragma unroll
  for (int s = 0; s < NSW; ++s) { a0[s] = 0.f; a1[s] = 0.f; }

  const float* xc = xT + (size_t)(fh * 128) * SP + col;
#pragma unroll 8
  for (int f = 0; f < 128; ++f) {
    float xv = xc[(size_t)f * SP];
#pragma unroll
    for (int s = 0; s < NSW; ++s) {
      float4 p = pl[s * FD + fh * 128 + f];  // wave-uniform -> LDS broadcast
      float e = entpair(p.x, xv);
      a0[s] = __builtin_fmaf(e, p.y, a0[s]);
      a1[s] = __builtin_fmaf(-e, p.z, a1[s]);
    }
  }
  if (fh == 1) {
    const float* pc = prevT + col;
#pragma unroll
    for (int o = 0; o < EX; ++o) {
      float pv = pc[(size_t)o * SP];
#pragma unroll
      for (int s = 0; s < NSW; ++s) {
        float4 p = pl[s * FD + 256 + o];
        float e = entpair(p.x, pv);
        a0[s] = __builtin_fmaf(e, p.y, a0[s]);
        a1[s] = __builtin_fmaf(-e, p.z, a1[s]);
      }
    }
#pragma unroll
    for (int s = 0; s < NSW; ++s) pb[s][lcol] = make_float2(a0[s], a1[s]);
  }
  __syncthreads();
  if (fh == 0) {
    float r0[NSW], r1[NSW];
#pragma unroll
    for (int s = 0; s < NSW; ++s) {
      float2 t = pb[s][lcol];
      r0[s] = a0[s] + t.x + cstL[2 * (s0 + s)];
      r1[s] = a1[s] + t.y + cstL[2 * (s0 + s) + 1];
    }
    if (FINAL) {
      // 2*NSW consecutive floats at out[col][2*s0 ...]
      float* op = outp + (size_t)col * 64 + 2 * s0;
#pragma unroll
      for (int s = 0; s < NSW; s += 2)
        *(float4*)(op + 2 * s) = make_float4(r0[s], r1[s], r0[s + 1], r1[s + 1]);
    } else {
#pragma unroll
      for (int s = 0; s < NSW; ++s) {
        outp[(size_t)(2 * (s0 + s)) * SP + col] = r0[s];
        outp[(size_t)(2 * (s0 + s) + 1) * SP + col] = r1[s];
      }
    }
  }
}

extern "C" void kernel_launch(void* const* d_in, const int* in_sizes, int n_in,
                              void* d_out, int out_size, void* d_ws, size_t ws_size,
                              hipStream_t stream) {
  const float* x = (const float*)d_in[0];
  float* out = (float*)d_out;
  float* wsf = (float*)d_ws;

  // ws layout (float offsets), padded stride SP
  float* xT = wsf + 0;                     // [256][SP]
  float* out2T = wsf + 2113536;            // [8][SP]
  float* out3T = wsf + 2179584;            // [16][SP]
  float* out4T = wsf + 2311680;            // [32][SP]
  float4* prm = (float4*)(wsf + 2575872);  // 17492 float4
  float* cstf = wsf + 2645840;             // 126 floats

  hipLaunchKernelGGL(ndt_transpose, dim3(8, B_SZ / 32), dim3(32, 8), 0, stream,
                     x, xT);

  MaskArgs ma;
  for (int d = 0; d < 6; ++d) {
    ma.fm[d] = (const float*)d_in[1 + 3 * d];
    ma.cp[d] = (const float*)d_in[2 + 3 * d];
    ma.lr[d] = (const float*)d_in[3 + 3 * d];
  }
  ma.out_masks = out;
  ma.prm = prm;
  ma.cstf = cstf;
  hipLaunchKernelGGL(ndt_masks, dim3(63), dim3(64), 0, stream, ma);

  // levels 0-2 fused (row-major x; writes out2T transposed, padded)
  hipLaunchKernelGGL(ndt_l012, dim3(B_SZ / 32), dim3(256), 0, stream,
                     x, prm, cstf, out2T);
  // level 3: 8 stumps; grid (32, 8), NSW=1
  hipLaunchKernelGGL((ndt_bigT<8, 1, false>), dim3(32, 8), dim3(512), 0, stream,
                     xT, out2T, prm + 1812, cstf + 14, out3T);
  // level 4: 16 stumps; grid (32, 8), NSW=2 (halves x re-reads)
  hipLaunchKernelGGL((ndt_bigT<16, 2, false>), dim3(32, 8), dim3(512), 0, stream,
                     xT, out3T, prm + 3924, cstf + 30, out4T);
  // level 5: 32 stumps; grid (32, 8), NSW=4 (quarters x re-reads), final write
  hipLaunchKernelGGL((ndt_bigT<32, 4, true>), dim3(32, 8), dim3(512), 0, stream,
                     xT, out4T, prm + 8276, cstf + 62, out);
}

// Round 12
// 78.922 us; speedup vs baseline: 1.0767x; 1.0767x over previous
//
#include <hip/hip_runtime.h>

#define B_SZ 8192
#define SP 8256  // padded row stride (floats): breaks 32KB power-of-2 L2-channel aliasing

// ---------------- transpose x [8192,256] -> xT [256][SP] ----------------
__global__ __launch_bounds__(256) void ndt_transpose(const float* __restrict__ x,
                                                     float* __restrict__ xT) {
  __shared__ float tile[32][33];
  int f0 = blockIdx.x * 32;
  int b0 = blockIdx.y * 32;
  int tx = threadIdx.x, ty = threadIdx.y;
#pragma unroll
  for (int k = 0; k < 32; k += 8)
    tile[ty + k][tx] = x[(size_t)(b0 + ty + k) * 256 + f0 + tx];
  __syncthreads();
#pragma unroll
  for (int k = 0; k < 32; k += 8)
    xT[(size_t)(f0 + ty + k) * SP + b0 + tx] = tile[tx][ty + k];
}

// ---------------- masks (exact 1.5-entmax via bisection) + fused params ----------------
struct MaskArgs {
  const float* fm[6];
  const float* cp[6];
  const float* lr[6];
  float* out_masks;  // d_out base
  float4* prm;       // fused params {c10, ml0/8, ml1/8, 0}
  float* cstf;       // flat per-output 0.5*sum(ml): level d at 2*cstOff[d]
};

__device__ __forceinline__ float wave_max(float v) {
#pragma unroll
  for (int o = 32; o > 0; o >>= 1) v = fmaxf(v, __shfl_xor(v, o));
  return v;
}
__device__ __forceinline__ float wave_sum(float v) {
#pragma unroll
  for (int o = 32; o > 0; o >>= 1) v += __shfl_xor(v, o);
  return v;
}

__global__ __launch_bounds__(64) void ndt_masks(MaskArgs a) {
  const int maskOff[6] = {524288, 524544, 525060, 526100, 528212, 532564};
  const int prmOff[6]  = {0, 256, 772, 1812, 3924, 8276};
  const int cstOff[6]  = {0, 1, 3, 7, 15, 31};
  int bid = blockIdx.x, lane = threadIdx.x;
  int d = 0, s = bid, n = 1;
  while (s >= n) { s -= n; n <<= 1; ++d; }   // level d, stump s, n = 2^d
  int Fd = 256 + ((d > 0) ? n : 0);

  const float* fm = a.fm[d] + (size_t)s * Fd;
  float y[5];
#pragma unroll
  for (int j = 0; j < 5; ++j) {
    int f = lane + 64 * j;
    y[j] = (f < Fd) ? fm[f] * 0.5f : -3.0e38f;
  }
  float m = fmaxf(fmaxf(fmaxf(y[0], y[1]), fmaxf(y[2], y[3])), y[4]);
  m = wave_max(m);
#pragma unroll
  for (int j = 0; j < 5; ++j) y[j] -= m;

  // solve sum clip(y - tau, 0)^2 = 1 ; tau in [-1, 0], strictly decreasing in tau
  float lo = -1.f, hi = 0.f;
  for (int it = 0; it < 24; ++it) {
    float tau = 0.5f * (lo + hi);
    float ss = 0.f;
#pragma unroll
    for (int j = 0; j < 5; ++j) {
      float v = fmaxf(y[j] - tau, 0.f);
      ss = __builtin_fmaf(v, v, ss);
    }
    ss = wave_sum(ss);
    if (ss >= 1.f) lo = tau; else hi = tau;
  }
  float tau = 0.5f * (lo + hi);

  float* mo = a.out_masks + maskOff[d] + (size_t)s * Fd;
  const float* cp = a.cp[d] + (size_t)s * Fd * 2;
  const float* lr = a.lr[d] + (size_t)s * Fd * 2;
  float4* pr = a.prm + prmOff[d] + (size_t)s * Fd;
  float sum0 = 0.f, sum1 = 0.f;
#pragma unroll
  for (int j = 0; j < 5; ++j) {
    int f = lane + 64 * j;
    if (f < Fd) {
      float v = fmaxf(y[j] - tau, 0.f);
      float mk = v * v;
      mo[f] = mk;
      float c0 = cp[2 * f], c1 = cp[2 * f + 1];
      float ml0 = lr[2 * f] * mk, ml1 = lr[2 * f + 1] * mk;
      sum0 += ml0;
      sum1 += ml1;
      // store ml/8: entpair returns e' = 8e, so e'*(ml/8) = e*ml
      pr[f] = make_float4(c1 - c0, ml0 * 0.125f, ml1 * 0.125f, 0.f);
    }
  }
  sum0 = wave_sum(sum0);
  sum1 = wave_sum(sum1);
  if (lane == 0) {
    a.cstf[2 * (cstOff[d] + s)] = 0.5f * sum0;
    a.cstf[2 * (cstOff[d] + s) + 1] = 0.5f * sum1;
  }
}

// 2-elem entmax15 closed form (scaled): t = c10 - x; tc = clamp(t,-2,2);
// e' = tc*sqrt(8 - tc^2) = 8*e;  p0 = 0.5 + e'/8, p1 = 0.5 - e'/8.
// The 1/8 is folded into the ml params at build time.
__device__ __forceinline__ float entpair(float c10, float xv) {
  float t = c10 - xv;
  float tc = __builtin_amdgcn_fmed3f(t, -2.f, 2.f);
  float u = __builtin_fmaf(tc, -tc, 8.0f);
  return tc * __builtin_amdgcn_sqrtf(u);
}

// ---------------- levels 0-2 fused: 32-row blocks, 8 groups x 32 lanes ----------------
// Writes out2 TRANSPOSED with padded stride: out2T[o][row], o in [0,8).
__global__ __launch_bounds__(256) void ndt_l012(const float* __restrict__ x,
                                                const float4* __restrict__ prm,
                                                const float* __restrict__ cstf,
                                                float* __restrict__ out2T) {
  __shared__ float xls[256 * 32];
  __shared__ float4 pl[1812];
  __shared__ float pbuf[8][2][32];
  int tid = threadIdx.x;
  int r = tid & 31, c = tid >> 5;
  int b0 = blockIdx.x * 32;
  for (int i = tid; i < 1812; i += 256) pl[i] = prm[i];
  {
    const float4* xp = (const float4*)(x + (size_t)(b0 + r) * 256 + c * 32);
#pragma unroll
    for (int j = 0; j < 8; ++j) {
      float4 g = xp[j];
      int f = c * 32 + 4 * j;
      xls[(f + 0) * 32 + (r ^ ((4 * j + 0) & 31))] = g.x;
      xls[(f + 1) * 32 + (r ^ ((4 * j + 1) & 31))] = g.y;
      xls[(f + 2) * 32 + (r ^ ((4 * j + 2) & 31))] = g.z;
      xls[(f + 3) * 32 + (r ^ ((4 * j + 3) & 31))] = g.w;
    }
  }
  __syncthreads();
  // ---- L0: group c -> features [c*32, c*32+32)
  float a0 = 0.f, a1 = 0.f;
#pragma unroll
  for (int j = 0; j < 32; ++j) {
    int f = c * 32 + j;
    float xv = xls[f * 32 + (r ^ j)];
    float4 p = pl[f];
    float e = entpair(p.x, xv);
    a0 = __builtin_fmaf(e, p.y, a0);
    a1 = __builtin_fmaf(-e, p.z, a1);
  }
  pbuf[c][0][r] = a0;
  pbuf[c][1][r] = a1;
  __syncthreads();
  float xe1[2];
#pragma unroll
  for (int o = 0; o < 2; ++o) {
    float v = cstf[o];
#pragma unroll
    for (int k = 0; k < 8; ++k) v += pbuf[k][o][r];
    xe1[o] = v;
  }
  __syncthreads();
  // ---- L1: stump c>>2, feature slice (c&3)*64; extras on slice 0
  {
    int s = c >> 2, fs = c & 3;
    const float4* ps = &pl[256 + s * 258];
    a0 = 0.f;
    a1 = 0.f;
#pragma unroll
    for (int j = 0; j < 64; ++j) {
      int f = fs * 64 + j;
      float xv = xls[f * 32 + (r ^ (f & 31))];
      float4 p = ps[f];
      float e = entpair(p.x, xv);
      a0 = __builtin_fmaf(e, p.y, a0);
      a1 = __builtin_fmaf(-e, p.z, a1);
    }
    if (fs == 0) {
#pragma unroll
      for (int o = 0; o < 2; ++o) {
        float4 p = ps[256 + o];
        float e = entpair(p.x, xe1[o]);
        a0 = __builtin_fmaf(e, p.y, a0);
        a1 = __builtin_fmaf(-e, p.z, a1);
      }
    }
    pbuf[c][0][r] = a0;
    pbuf[c][1][r] = a1;
  }
  __syncthreads();
  float xe2[4];
#pragma unroll
  for (int s = 0; s < 2; ++s)
#pragma unroll
    for (int o = 0; o < 2; ++o) {
      float v = cstf[2 + 2 * s + o];
#pragma unroll
      for (int k = 0; k < 4; ++k) v += pbuf[4 * s + k][o][r];
      xe2[2 * s + o] = v;
    }
  __syncthreads();
  // ---- L2: stump c>>1, feature slice (c&1)*128; extras on slice 0
  {
    int s = c >> 1, fs = c & 1;
    const float4* ps = &pl[772 + s * 260];
    a0 = 0.f;
    a1 = 0.f;
#pragma unroll
    for (int j = 0; j < 128; ++j) {
      int f = fs * 128 + j;
      float xv = xls[f * 32 + (r ^ (f & 31))];
      float4 p = ps[f];
      float e = entpair(p.x, xv);
      a0 = __builtin_fmaf(e, p.y, a0);
      a1 = __builtin_fmaf(-e, p.z, a1);
    }
    if (fs == 0) {
#pragma unroll
      for (int o = 0; o < 4; ++o) {
        float4 p = ps[256 + o];
        float e = entpair(p.x, xe2[o]);
        a0 = __builtin_fmaf(e, p.y, a0);
        a1 = __builtin_fmaf(-e, p.z, a1);
      }
    }
    pbuf[c][0][r] = a0;
    pbuf[c][1][r] = a1;
  }
  __syncthreads();
  // ---- reduce L2 -> out2T[4c+i][b0+r]
  if (c < 2) {
#pragma unroll
    for (int i = 0; i < 4; ++i) {
      int s = 2 * c + (i >> 1), o = i & 1;
      float v = cstf[6 + 2 * s + o];
#pragma unroll
      for (int k = 0; k < 2; ++k) v += pbuf[2 * s + k][o][r];
      out2T[(size_t)(4 * c + i) * SP + b0 + r] = v;
    }
  }
}

// ---------------- big levels (3,4,5): feature-major, 64 cols x 4 f-groups ----------
// Block = 256 thr: wave fh in [0,4) handles features [fh*64,(fh+1)*64) for 64 cols
// (lcol = lane). Wave 3 also does the EX prev-level features. Partials combine via
// a small LDS buffer. Params in LDS (wave-uniform broadcast). NSW stumps share each
// x load. Grid (128 colblks, n/NSW) -> 1024-2048 blocks: occupancy is grid-fed.
template <int EX, int NSW, bool FINAL>
__global__ __launch_bounds__(256, 8) void ndt_bigT(const float* __restrict__ xT,
                                                   const float* __restrict__ prevT,
                                                   const float4* __restrict__ prmL,
                                                   const float* __restrict__ cstL,
                                                   float* __restrict__ outp) {
  constexpr int FD = 256 + EX;
  __shared__ float4 pl[NSW * FD];
  __shared__ float2 pb[NSW][3][64];
  int tid = threadIdx.x;
  int lcol = tid & 63, fh = tid >> 6;  // wave-aligned f-groups
  int s0 = blockIdx.y * NSW;
  for (int i = tid; i < NSW * FD; i += 256) pl[i] = prmL[(size_t)s0 * FD + i];
  __syncthreads();

  int col = blockIdx.x * 64 + lcol;
  float a0[NSW], a1[NSW];
#pragma unroll
  for (int s = 0; s < NSW; ++s) { a0[s] = 0.f; a1[s] = 0.f; }

  const float* xc = xT + (size_t)(fh * 64) * SP + col;
#pragma unroll 8
  for (int f = 0; f < 64; ++f) {
    float xv = xc[(size_t)f * SP];
#pragma unroll
    for (int s = 0; s < NSW; ++s) {
      float4 p = pl[s * FD + fh * 64 + f];  // wave-uniform -> LDS broadcast
      float e = entpair(p.x, xv);
      a0[s] = __builtin_fmaf(e, p.y, a0[s]);
      a1[s] = __builtin_fmaf(-e, p.z, a1[s]);
    }
  }
  if (fh == 3) {
    const float* pc = prevT + col;
#pragma unroll
    for (int o = 0; o < EX; ++o) {
      float pv = pc[(size_t)o * SP];
#pragma unroll
      for (int s = 0; s < NSW; ++s) {
        float4 p = pl[s * FD + 256 + o];
        float e = entpair(p.x, pv);
        a0[s] = __builtin_fmaf(e, p.y, a0[s]);
        a1[s] = __builtin_fmaf(-e, p.z, a1[s]);
      }
    }
  }
  if (fh > 0) {
#pragma unroll
    for (int s = 0; s < NSW; ++s) pb[s][fh - 1][lcol] = make_float2(a0[s], a1[s]);
  }
  __syncthreads();
  if (fh == 0) {
    float r0[NSW], r1[NSW];
#pragma unroll
    for (int s = 0; s < NSW; ++s) {
      r0[s] = a0[s] + cstL[2 * (s0 + s)];
      r1[s] = a1[s] + cstL[2 * (s0 + s) + 1];
#pragma unroll
      for (int k = 0; k < 3; ++k) {
        float2 t = pb[s][k][lcol];
        r0[s] += t.x;
        r1[s] += t.y;
      }
    }
    if (FINAL) {
      // 2*NSW consecutive floats at out[col][2*s0 ...]
      float* op = outp + (size_t)col * 64 + 2 * s0;
#pragma unroll
      for (int s = 0; s < NSW; s += 2)
        *(float4*)(op + 2 * s) = make_float4(r0[s], r1[s], r0[s + 1], r1[s + 1]);
    } else {
#pragma unroll
      for (int s = 0; s < NSW; ++s) {
        outp[(size_t)(2 * (s0 + s)) * SP + col] = r0[s];
        outp[(size_t)(2 * (s0 + s) + 1) * SP + col] = r1[s];
      }
    }
  }
}

extern "C" void kernel_launch(void* const* d_in, const int* in_sizes, int n_in,
                              void* d_out, int out_size, void* d_ws, size_t ws_size,
                              hipStream_t stream) {
  const float* x = (const float*)d_in[0];
  float* out = (float*)d_out;
  float* wsf = (float*)d_ws;

  // ws layout (float offsets), padded stride SP
  float* xT = wsf + 0;                     // [256][SP]
  float* out2T = wsf + 2113536;            // [8][SP]
  float* out3T = wsf + 2179584;            // [16][SP]
  float* out4T = wsf + 2311680;            // [32][SP]
  float4* prm = (float4*)(wsf + 2575872);  // 17492 float4
  float* cstf = wsf + 2645840;             // 126 floats

  hipLaunchKernelGGL(ndt_transpose, dim3(8, B_SZ / 32), dim3(32, 8), 0, stream,
                     x, xT);

  MaskArgs ma;
  for (int d = 0; d < 6; ++d) {
    ma.fm[d] = (const float*)d_in[1 + 3 * d];
    ma.cp[d] = (const float*)d_in[2 + 3 * d];
    ma.lr[d] = (const float*)d_in[3 + 3 * d];
  }
  ma.out_masks = out;
  ma.prm = prm;
  ma.cstf = cstf;
  hipLaunchKernelGGL(ndt_masks, dim3(63), dim3(64), 0, stream, ma);

  // levels 0-2 fused (row-major x; writes out2T transposed, padded)
  hipLaunchKernelGGL(ndt_l012, dim3(B_SZ / 32), dim3(256), 0, stream,
                     x, prm, cstf, out2T);
  // level 3: 8 stumps; grid (128, 8) = 1024 blocks
  hipLaunchKernelGGL((ndt_bigT<8, 1, false>), dim3(128, 8), dim3(256), 0, stream,
                     xT, out2T, prm + 1812, cstf + 14, out3T);
  // level 4: 16 stumps; grid (128, 16) = 2048 blocks
  hipLaunchKernelGGL((ndt_bigT<16, 1, false>), dim3(128, 16), dim3(256), 0, stream,
                     xT, out3T, prm + 3924, cstf + 30, out4T);
  // level 5: 32 stumps; grid (128, 16) = 2048 blocks, NSW=2, final write
  hipLaunchKernelGGL((ndt_bigT<32, 2, true>), dim3(128, 16), dim3(256), 0, stream,
                     xT, out4T, prm + 8276, cstf + 62, out);
}

// Round 13
// 73.992 us; speedup vs baseline: 1.1485x; 1.0666x over previous
//
#include <hip/hip_runtime.h>

#define B_SZ 8192
#define SP 8256  // padded row stride (floats): breaks 32KB power-of-2 L2-channel aliasing

// ---------------- transpose x [8192,256] -> xT [256][SP] ----------------
__global__ __launch_bounds__(256) void ndt_transpose(const float* __restrict__ x,
                                                     float* __restrict__ xT) {
  __shared__ float tile[32][33];
  int f0 = blockIdx.x * 32;
  int b0 = blockIdx.y * 32;
  int tx = threadIdx.x, ty = threadIdx.y;
#pragma unroll
  for (int k = 0; k < 32; k += 8)
    tile[ty + k][tx] = x[(size_t)(b0 + ty + k) * 256 + f0 + tx];
  __syncthreads();
#pragma unroll
  for (int k = 0; k < 32; k += 8)
    xT[(size_t)(f0 + ty + k) * SP + b0 + tx] = tile[tx][ty + k];
}

// ---------------- masks (exact 1.5-entmax via bisection) + fused params ----------------
struct MaskArgs {
  const float* fm[6];
  const float* cp[6];
  const float* lr[6];
  float* out_masks;  // d_out base
  float4* prm;       // fused params {c10, ml0/8, ml1/8, 0}
  float* cstf;       // flat per-output 0.5*sum(ml): level d at 2*cstOff[d]
};

__device__ __forceinline__ float wave_max(float v) {
#pragma unroll
  for (int o = 32; o > 0; o >>= 1) v = fmaxf(v, __shfl_xor(v, o));
  return v;
}
__device__ __forceinline__ float wave_sum(float v) {
#pragma unroll
  for (int o = 32; o > 0; o >>= 1) v += __shfl_xor(v, o);
  return v;
}

__global__ __launch_bounds__(64) void ndt_masks(MaskArgs a) {
  const int maskOff[6] = {524288, 524544, 525060, 526100, 528212, 532564};
  const int prmOff[6]  = {0, 256, 772, 1812, 3924, 8276};
  const int cstOff[6]  = {0, 1, 3, 7, 15, 31};
  int bid = blockIdx.x, lane = threadIdx.x;
  int d = 0, s = bid, n = 1;
  while (s >= n) { s -= n; n <<= 1; ++d; }   // level d, stump s, n = 2^d
  int Fd = 256 + ((d > 0) ? n : 0);

  const float* fm = a.fm[d] + (size_t)s * Fd;
  float y[5];
#pragma unroll
  for (int j = 0; j < 5; ++j) {
    int f = lane + 64 * j;
    y[j] = (f < Fd) ? fm[f] * 0.5f : -3.0e38f;
  }
  float m = fmaxf(fmaxf(fmaxf(y[0], y[1]), fmaxf(y[2], y[3])), y[4]);
  m = wave_max(m);
#pragma unroll
  for (int j = 0; j < 5; ++j) y[j] -= m;

  // solve sum clip(y - tau, 0)^2 = 1 ; tau in [-1, 0], strictly decreasing in tau
  float lo = -1.f, hi = 0.f;
  for (int it = 0; it < 24; ++it) {
    float tau = 0.5f * (lo + hi);
    float ss = 0.f;
#pragma unroll
    for (int j = 0; j < 5; ++j) {
      float v = fmaxf(y[j] - tau, 0.f);
      ss = __builtin_fmaf(v, v, ss);
    }
    ss = wave_sum(ss);
    if (ss >= 1.f) lo = tau; else hi = tau;
  }
  float tau = 0.5f * (lo + hi);

  float* mo = a.out_masks + maskOff[d] + (size_t)s * Fd;
  const float* cp = a.cp[d] + (size_t)s * Fd * 2;
  const float* lr = a.lr[d] + (size_t)s * Fd * 2;
  float4* pr = a.prm + prmOff[d] + (size_t)s * Fd;
  float sum0 = 0.f, sum1 = 0.f;
#pragma unroll
  for (int j = 0; j < 5; ++j) {
    int f = lane + 64 * j;
    if (f < Fd) {
      float v = fmaxf(y[j] - tau, 0.f);
      float mk = v * v;
      mo[f] = mk;
      float c0 = cp[2 * f], c1 = cp[2 * f + 1];
      float ml0 = lr[2 * f] * mk, ml1 = lr[2 * f + 1] * mk;
      sum0 += ml0;
      sum1 += ml1;
      // store ml/8: entpair returns e' = 8e, so e'*(ml/8) = e*ml
      pr[f] = make_float4(c1 - c0, ml0 * 0.125f, ml1 * 0.125f, 0.f);
    }
  }
  sum0 = wave_sum(sum0);
  sum1 = wave_sum(sum1);
  if (lane == 0) {
    a.cstf[2 * (cstOff[d] + s)] = 0.5f * sum0;
    a.cstf[2 * (cstOff[d] + s) + 1] = 0.5f * sum1;
  }
}

// 2-elem entmax15 closed form (scaled): t = c10 - x; tc = clamp(t,-2,2);
// e' = tc*sqrt(8 - tc^2) = 8*e;  p0 = 0.5 + e'/8, p1 = 0.5 - e'/8.
// The 1/8 is folded into the ml params at build time.
__device__ __forceinline__ float entpair(float c10, float xv) {
  float t = c10 - xv;
  float tc = __builtin_amdgcn_fmed3f(t, -2.f, 2.f);
  float u = __builtin_fmaf(tc, -tc, 8.0f);
  return tc * __builtin_amdgcn_sqrtf(u);
}

// ---------------- levels 0-2 fused: 32-row blocks, 8 groups x 32 lanes ----------------
// Writes out2 TRANSPOSED with padded stride: out2T[o][row], o in [0,8).
__global__ __launch_bounds__(256) void ndt_l012(const float* __restrict__ x,
                                                const float4* __restrict__ prm,
                                                const float* __restrict__ cstf,
                                                float* __restrict__ out2T) {
  __shared__ float xls[256 * 32];
  __shared__ float4 pl[1812];
  __shared__ float pbuf[8][2][32];
  int tid = threadIdx.x;
  int r = tid & 31, c = tid >> 5;
  int b0 = blockIdx.x * 32;
  for (int i = tid; i < 1812; i += 256) pl[i] = prm[i];
  {
    const float4* xp = (const float4*)(x + (size_t)(b0 + r) * 256 + c * 32);
#pragma unroll
    for (int j = 0; j < 8; ++j) {
      float4 g = xp[j];
      int f = c * 32 + 4 * j;
      xls[(f + 0) * 32 + (r ^ ((4 * j + 0) & 31))] = g.x;
      xls[(f + 1) * 32 + (r ^ ((4 * j + 1) & 31))] = g.y;
      xls[(f + 2) * 32 + (r ^ ((4 * j + 2) & 31))] = g.z;
      xls[(f + 3) * 32 + (r ^ ((4 * j + 3) & 31))] = g.w;
    }
  }
  __syncthreads();
  // ---- L0: group c -> features [c*32, c*32+32)
  float a0 = 0.f, a1 = 0.f;
#pragma unroll
  for (int j = 0; j < 32; ++j) {
    int f = c * 32 + j;
    float xv = xls[f * 32 + (r ^ j)];
    float4 p = pl[f];
    float e = entpair(p.x, xv);
    a0 = __builtin_fmaf(e, p.y, a0);
    a1 = __builtin_fmaf(-e, p.z, a1);
  }
  pbuf[c][0][r] = a0;
  pbuf[c][1][r] = a1;
  __syncthreads();
  float xe1[2];
#pragma unroll
  for (int o = 0; o < 2; ++o) {
    float v = cstf[o];
#pragma unroll
    for (int k = 0; k < 8; ++k) v += pbuf[k][o][r];
    xe1[o] = v;
  }
  __syncthreads();
  // ---- L1: stump c>>2, feature slice (c&3)*64; extras on slice 0
  {
    int s = c >> 2, fs = c & 3;
    const float4* ps = &pl[256 + s * 258];
    a0 = 0.f;
    a1 = 0.f;
#pragma unroll
    for (int j = 0; j < 64; ++j) {
      int f = fs * 64 + j;
      float xv = xls[f * 32 + (r ^ (f & 31))];
      float4 p = ps[f];
      float e = entpair(p.x, xv);
      a0 = __builtin_fmaf(e, p.y, a0);
      a1 = __builtin_fmaf(-e, p.z, a1);
    }
    if (fs == 0) {
#pragma unroll
      for (int o = 0; o < 2; ++o) {
        float4 p = ps[256 + o];
        float e = entpair(p.x, xe1[o]);
        a0 = __builtin_fmaf(e, p.y, a0);
        a1 = __builtin_fmaf(-e, p.z, a1);
      }
    }
    pbuf[c][0][r] = a0;
    pbuf[c][1][r] = a1;
  }
  __syncthreads();
  float xe2[4];
#pragma unroll
  for (int s = 0; s < 2; ++s)
#pragma unroll
    for (int o = 0; o < 2; ++o) {
      float v = cstf[2 + 2 * s + o];
#pragma unroll
      for (int k = 0; k < 4; ++k) v += pbuf[4 * s + k][o][r];
      xe2[2 * s + o] = v;
    }
  __syncthreads();
  // ---- L2: stump c>>1, feature slice (c&1)*128; extras on slice 0
  {
    int s = c >> 1, fs = c & 1;
    const float4* ps = &pl[772 + s * 260];
    a0 = 0.f;
    a1 = 0.f;
#pragma unroll
    for (int j = 0; j < 128; ++j) {
      int f = fs * 128 + j;
      float xv = xls[f * 32 + (r ^ (f & 31))];
      float4 p = ps[f];
      float e = entpair(p.x, xv);
      a0 = __builtin_fmaf(e, p.y, a0);
      a1 = __builtin_fmaf(-e, p.z, a1);
    }
    if (fs == 0) {
#pragma unroll
      for (int o = 0; o < 4; ++o) {
        float4 p = ps[256 + o];
        float e = entpair(p.x, xe2[o]);
        a0 = __builtin_fmaf(e, p.y, a0);
        a1 = __builtin_fmaf(-e, p.z, a1);
      }
    }
    pbuf[c][0][r] = a0;
    pbuf[c][1][r] = a1;
  }
  __syncthreads();
  // ---- reduce L2 -> out2T[4c+i][b0+r]
  if (c < 2) {
#pragma unroll
    for (int i = 0; i < 4; ++i) {
      int s = 2 * c + (i >> 1), o = i & 1;
      float v = cstf[6 + 2 * s + o];
#pragma unroll
      for (int k = 0; k < 2; ++k) v += pbuf[2 * s + k][o][r];
      out2T[(size_t)(4 * c + i) * SP + b0 + r] = v;
    }
  }
}

// ---------------- big levels (3,4,5): column-blocked, 8 f-groups ----------
// Block = 512 thr = 8 waves; wave fh handles base features [fh*32, fh*32+32) AND
// extras [fh*EX/8, ...) (balanced). Each lane owns C CONSECUTIVE columns: one
// global_load_dwordx4 + NSW ds_read_b128 broadcast feed C*NSW pair-ops (4x fewer
// DS/VMEM instructions than 1 col/lane). Partials combine via LDS; cst folded
// into group-0 init. Grid (8192/(64C), n/NSW) = 512 blocks = 16 waves/CU.
template <int EX, int NSW, int C, bool FINAL>
__global__ __launch_bounds__(512, 4) void ndt_bigT(const float* __restrict__ xT,
                                                   const float* __restrict__ prevT,
                                                   const float4* __restrict__ prmL,
                                                   const float* __restrict__ cstL,
                                                   float* __restrict__ outp) {
  constexpr int FD = 256 + EX;
  constexpr int FPG = 32;       // base features per group
  constexpr int EXPG = EX / 8;  // extra features per group
  constexpr int COLS = 64 * C;
  __shared__ float4 pl[NSW * FD];
  __shared__ float2 pb[NSW][7][COLS];
  int tid = threadIdx.x;
  int lane = tid & 63, fh = tid >> 6;
  int s0 = blockIdx.y * NSW;
  for (int i = tid; i < NSW * FD; i += 512) pl[i] = prmL[(size_t)s0 * FD + i];
  __syncthreads();

  int colBase = blockIdx.x * COLS + C * lane;
  float a0[NSW][C], a1[NSW][C];
#pragma unroll
  for (int s = 0; s < NSW; ++s) {
    float c0 = (fh == 0) ? cstL[2 * (s0 + s)] : 0.f;
    float c1 = (fh == 0) ? cstL[2 * (s0 + s) + 1] : 0.f;
#pragma unroll
    for (int c = 0; c < C; ++c) {
      a0[s][c] = c0;
      a1[s][c] = c1;
    }
  }

  const float* xc = xT + (size_t)(fh * FPG) * SP + colBase;
#pragma unroll 8
  for (int f = 0; f < FPG; ++f) {
    float xv[C];
    if (C == 4) {
      float4 g = *(const float4*)(xc + (size_t)f * SP);
      xv[0] = g.x; xv[1] = g.y; xv[2] = g.z; xv[3] = g.w;
    } else {
      float2 g = *(const float2*)(xc + (size_t)f * SP);
      xv[0] = g.x; xv[1] = g.y;
    }
    int fg = fh * FPG + f;
#pragma unroll
    for (int s = 0; s < NSW; ++s) {
      float4 p = pl[s * FD + fg];  // wave-uniform -> LDS broadcast
#pragma unroll
      for (int c = 0; c < C; ++c) {
        float e = entpair(p.x, xv[c]);
        a0[s][c] = __builtin_fmaf(e, p.y, a0[s][c]);
        a1[s][c] = __builtin_fmaf(-e, p.z, a1[s][c]);
      }
    }
  }
  // extras: prev-level outputs, EXPG per group (balanced)
  {
    const float* pc = prevT + (size_t)(fh * EXPG) * SP + colBase;
#pragma unroll
    for (int o = 0; o < EXPG; ++o) {
      float xv[C];
      if (C == 4) {
        float4 g = *(const float4*)(pc + (size_t)o * SP);
        xv[0] = g.x; xv[1] = g.y; xv[2] = g.z; xv[3] = g.w;
      } else {
        float2 g = *(const float2*)(pc + (size_t)o * SP);
        xv[0] = g.x; xv[1] = g.y;
      }
      int fo = 256 + fh * EXPG + o;
#pragma unroll
      for (int s = 0; s < NSW; ++s) {
        float4 p = pl[s * FD + fo];
#pragma unroll
        for (int c = 0; c < C; ++c) {
          float e = entpair(p.x, xv[c]);
          a0[s][c] = __builtin_fmaf(e, p.y, a0[s][c]);
          a1[s][c] = __builtin_fmaf(-e, p.z, a1[s][c]);
        }
      }
    }
  }
  if (fh > 0) {
#pragma unroll
    for (int s = 0; s < NSW; ++s)
#pragma unroll
      for (int c = 0; c < C; ++c)
        pb[s][fh - 1][C * lane + c] = make_float2(a0[s][c], a1[s][c]);
  }
  __syncthreads();
  if (fh == 0) {
#pragma unroll
    for (int s = 0; s < NSW; ++s)
#pragma unroll
      for (int c = 0; c < C; ++c) {
#pragma unroll
        for (int g = 0; g < 7; ++g) {
          float2 t = pb[s][g][C * lane + c];
          a0[s][c] += t.x;
          a1[s][c] += t.y;
        }
      }
    if (FINAL) {
      // NSW=2: 4 consecutive floats per column at out[col][2*s0]
#pragma unroll
      for (int c = 0; c < C; ++c) {
        float* op = outp + (size_t)(colBase + c) * 64 + 2 * s0;
        *(float4*)op = make_float4(a0[0][c], a1[0][c], a0[1][c], a1[1][c]);
      }
    } else {
#pragma unroll
      for (int s = 0; s < NSW; ++s) {
        float* o0 = outp + (size_t)(2 * (s0 + s)) * SP + colBase;
        float* o1 = outp + (size_t)(2 * (s0 + s) + 1) * SP + colBase;
        if (C == 4) {
          *(float4*)o0 = make_float4(a0[s][0], a0[s][1], a0[s][2], a0[s][3]);
          *(float4*)o1 = make_float4(a1[s][0], a1[s][1], a1[s][2], a1[s][3]);
        } else {
          *(float2*)o0 = make_float2(a0[s][0], a0[s][1]);
          *(float2*)o1 = make_float2(a1[s][0], a1[s][1]);
        }
      }
    }
  }
}

extern "C" void kernel_launch(void* const* d_in, const int* in_sizes, int n_in,
                              void* d_out, int out_size, void* d_ws, size_t ws_size,
                              hipStream_t stream) {
  const float* x = (const float*)d_in[0];
  float* out = (float*)d_out;
  float* wsf = (float*)d_ws;

  // ws layout (float offsets), padded stride SP
  float* xT = wsf + 0;                     // [256][SP]
  float* out2T = wsf + 2113536;            // [8][SP]
  float* out3T = wsf + 2179584;            // [16][SP]
  float* out4T = wsf + 2311680;            // [32][SP]
  float4* prm = (float4*)(wsf + 2575872);  // 17492 float4
  float* cstf = wsf + 2645840;             // 126 floats

  hipLaunchKernelGGL(ndt_transpose, dim3(8, B_SZ / 32), dim3(32, 8), 0, stream,
                     x, xT);

  MaskArgs ma;
  for (int d = 0; d < 6; ++d) {
    ma.fm[d] = (const float*)d_in[1 + 3 * d];
    ma.cp[d] = (const float*)d_in[2 + 3 * d];
    ma.lr[d] = (const float*)d_in[3 + 3 * d];
  }
  ma.out_masks = out;
  ma.prm = prm;
  ma.cstf = cstf;
  hipLaunchKernelGGL(ndt_masks, dim3(63), dim3(64), 0, stream, ma);

  // levels 0-2 fused (row-major x; writes out2T transposed, padded)
  hipLaunchKernelGGL(ndt_l012, dim3(B_SZ / 32), dim3(256), 0, stream,
                     x, prm, cstf, out2T);
  // level 3: 8 stumps; C=2 -> 128 cols/block; grid (64, 8) = 512 blocks
  hipLaunchKernelGGL((ndt_bigT<8, 1, 2, false>), dim3(64, 8), dim3(512), 0, stream,
                     xT, out2T, prm + 1812, cstf + 14, out3T);
  // level 4: 16 stumps; C=4 -> 256 cols/block; grid (32, 16) = 512 blocks
  hipLaunchKernelGGL((ndt_bigT<16, 1, 4, false>), dim3(32, 16), dim3(512), 0, stream,
                     xT, out3T, prm + 3924, cstf + 30, out4T);
  // level 5: 32 stumps; C=4, NSW=2; grid (32, 16) = 512 blocks, final write
  hipLaunchKernelGGL((ndt_bigT<32, 2, 4, true>), dim3(32, 16), dim3(512), 0, stream,
                     xT, out4T, prm + 8276, cstf + 62, out);
}

// Round 14
// 55.870 us; speedup vs baseline: 1.5210x; 1.3244x over previous
//
#include <hip/hip_runtime.h>

#define B_SZ 8192
#define SP 8256  // padded row stride (floats)

// ---------------- transpose x [8192,256] -> xAll rows 0..255 ----------------
__global__ __launch_bounds__(256) void ndt_transpose(const float* __restrict__ x,
                                                     float* __restrict__ xT) {
  __shared__ float tile[32][33];
  int f0 = blockIdx.x * 32;
  int b0 = blockIdx.y * 32;
  int tx = threadIdx.x, ty = threadIdx.y;
#pragma unroll
  for (int k = 0; k < 32; k += 8)
    tile[ty + k][tx] = x[(size_t)(b0 + ty + k) * 256 + f0 + tx];
  __syncthreads();
#pragma unroll
  for (int k = 0; k < 32; k += 8)
    xT[(size_t)(f0 + ty + k) * SP + b0 + tx] = tile[tx][ty + k];
}

// ---------------- masks + fused params (full for L0-2, COMPACTED for L3-5) ----------
struct MaskArgs {
  const float* fm[6];
  const float* cp[6];
  const float* lr[6];
  float* out_masks;  // d_out base
  float4* prm;       // full params {c10, ml0/8, ml1/8, 0} (used by l012)
  float4* cprm;      // compacted params {c10, ml0/8, ml1/8, fidx} (L3-5)
  int* cnt;          // compacted count per stump (global stump idx)
  float* cstf;       // per-output 0.5*sum(ml)
};

__device__ __forceinline__ float wave_max(float v) {
#pragma unroll
  for (int o = 32; o > 0; o >>= 1) v = fmaxf(v, __shfl_xor(v, o));
  return v;
}
__device__ __forceinline__ float wave_sum(float v) {
#pragma unroll
  for (int o = 32; o > 0; o >>= 1) v += __shfl_xor(v, o);
  return v;
}

__global__ __launch_bounds__(64) void ndt_masks(MaskArgs a) {
  const int maskOff[6] = {524288, 524544, 525060, 526100, 528212, 532564};
  const int prmOff[6]  = {0, 256, 772, 1812, 3924, 8276};
  const int cstOff[6]  = {0, 1, 3, 7, 15, 31};
  const int exBase[6]  = {0, 0, 0, 256, 264, 280};  // xAll row of extra feature 0
  int bid = blockIdx.x, lane = threadIdx.x;
  int d = 0, s = bid, n = 1;
  while (s >= n) { s -= n; n <<= 1; ++d; }   // level d, stump s, n = 2^d
  int Fd = 256 + ((d > 0) ? n : 0);

  const float* fm = a.fm[d] + (size_t)s * Fd;
  float y[5];
#pragma unroll
  for (int j = 0; j < 5; ++j) {
    int f = lane + 64 * j;
    y[j] = (f < Fd) ? fm[f] * 0.5f : -3.0e38f;
  }
  float m = fmaxf(fmaxf(fmaxf(y[0], y[1]), fmaxf(y[2], y[3])), y[4]);
  m = wave_max(m);
#pragma unroll
  for (int j = 0; j < 5; ++j) y[j] -= m;

  float lo = -1.f, hi = 0.f;
  for (int it = 0; it < 24; ++it) {
    float tau = 0.5f * (lo + hi);
    float ss = 0.f;
#pragma unroll
    for (int j = 0; j < 5; ++j) {
      float v = fmaxf(y[j] - tau, 0.f);
      ss = __builtin_fmaf(v, v, ss);
    }
    ss = wave_sum(ss);
    if (ss >= 1.f) lo = tau; else hi = tau;
  }
  float tau = 0.5f * (lo + hi);

  float* mo = a.out_masks + maskOff[d] + (size_t)s * Fd;
  const float* cp = a.cp[d] + (size_t)s * Fd * 2;
  const float* lr = a.lr[d] + (size_t)s * Fd * 2;
  float4* pr = a.prm + prmOff[d] + (size_t)s * Fd;
  float4* cpr = a.cprm + prmOff[d] + (size_t)s * Fd;
  int exB = exBase[d];
  float sum0 = 0.f, sum1 = 0.f;
  int base = 0;
#pragma unroll
  for (int j = 0; j < 5; ++j) {
    int f = lane + 64 * j;
    bool in = (f < Fd);
    float v = fmaxf(y[j] - tau, 0.f);
    float mk = v * v;
    float c10 = 0.f, ml0 = 0.f, ml1 = 0.f;
    if (in) {
      mo[f] = mk;
      float c0 = cp[2 * f], c1 = cp[2 * f + 1];
      ml0 = lr[2 * f] * mk;
      ml1 = lr[2 * f + 1] * mk;
      c10 = c1 - c0;
      sum0 += ml0;
      sum1 += ml1;
      pr[f] = make_float4(c10, ml0 * 0.125f, ml1 * 0.125f, 0.f);
    }
    bool act = in && (v > 0.f);
    unsigned long long bm = __ballot(act);
    int pre = __popcll(bm & ((1ull << lane) - 1ull));
    if (act) {
      int fidx = (f < 256) ? f : (exB + f - 256);
      cpr[base + pre] =
          make_float4(c10, ml0 * 0.125f, ml1 * 0.125f, __int_as_float(fidx));
    }
    base += __popcll(bm);
  }
  sum0 = wave_sum(sum0);
  sum1 = wave_sum(sum1);
  if (lane == 0) {
    a.cstf[2 * (cstOff[d] + s)] = 0.5f * sum0;
    a.cstf[2 * (cstOff[d] + s) + 1] = 0.5f * sum1;
    a.cnt[cstOff[d] + s] = base;
  }
}

// 2-elem entmax15 closed form (scaled): t = c10 - x; tc = clamp(t,-2,2);
// e' = tc*sqrt(8 - tc^2) = 8*e. The 1/8 is folded into ml at build time.
__device__ __forceinline__ float entpair(float c10, float xv) {
  float t = c10 - xv;
  float tc = __builtin_amdgcn_fmed3f(t, -2.f, 2.f);
  float u = __builtin_fmaf(tc, -tc, 8.0f);
  return tc * __builtin_amdgcn_sqrtf(u);
}

// ---------------- levels 0-2 fused: 32-row blocks, 8 groups x 32 lanes ----------------
__global__ __launch_bounds__(256) void ndt_l012(const float* __restrict__ x,
                                                const float4* __restrict__ prm,
                                                const float* __restrict__ cstf,
                                                float* __restrict__ out2T) {
  __shared__ float xls[256 * 32];
  __shared__ float4 pl[1812];
  __shared__ float pbuf[8][2][32];
  int tid = threadIdx.x;
  int r = tid & 31, c = tid >> 5;
  int b0 = blockIdx.x * 32;
  for (int i = tid; i < 1812; i += 256) pl[i] = prm[i];
  {
    const float4* xp = (const float4*)(x + (size_t)(b0 + r) * 256 + c * 32);
#pragma unroll
    for (int j = 0; j < 8; ++j) {
      float4 g = xp[j];
      int f = c * 32 + 4 * j;
      xls[(f + 0) * 32 + (r ^ ((4 * j + 0) & 31))] = g.x;
      xls[(f + 1) * 32 + (r ^ ((4 * j + 1) & 31))] = g.y;
      xls[(f + 2) * 32 + (r ^ ((4 * j + 2) & 31))] = g.z;
      xls[(f + 3) * 32 + (r ^ ((4 * j + 3) & 31))] = g.w;
    }
  }
  __syncthreads();
  float a0 = 0.f, a1 = 0.f;
#pragma unroll
  for (int j = 0; j < 32; ++j) {
    int f = c * 32 + j;
    float xv = xls[f * 32 + (r ^ j)];
    float4 p = pl[f];
    float e = entpair(p.x, xv);
    a0 = __builtin_fmaf(e, p.y, a0);
    a1 = __builtin_fmaf(-e, p.z, a1);
  }
  pbuf[c][0][r] = a0;
  pbuf[c][1][r] = a1;
  __syncthreads();
  float xe1[2];
#pragma unroll
  for (int o = 0; o < 2; ++o) {
    float v = cstf[o];
#pragma unroll
    for (int k = 0; k < 8; ++k) v += pbuf[k][o][r];
    xe1[o] = v;
  }
  __syncthreads();
  {
    int s = c >> 2, fs = c & 3;
    const float4* ps = &pl[256 + s * 258];
    a0 = 0.f;
    a1 = 0.f;
#pragma unroll
    for (int j = 0; j < 64; ++j) {
      int f = fs * 64 + j;
      float xv = xls[f * 32 + (r ^ (f & 31))];
      float4 p = ps[f];
      float e = entpair(p.x, xv);
      a0 = __builtin_fmaf(e, p.y, a0);
      a1 = __builtin_fmaf(-e, p.z, a1);
    }
    if (fs == 0) {
#pragma unroll
      for (int o = 0; o < 2; ++o) {
        float4 p = ps[256 + o];
        float e = entpair(p.x, xe1[o]);
        a0 = __builtin_fmaf(e, p.y, a0);
        a1 = __builtin_fmaf(-e, p.z, a1);
      }
    }
    pbuf[c][0][r] = a0;
    pbuf[c][1][r] = a1;
  }
  __syncthreads();
  float xe2[4];
#pragma unroll
  for (int s = 0; s < 2; ++s)
#pragma unroll
    for (int o = 0; o < 2; ++o) {
      float v = cstf[2 + 2 * s + o];
#pragma unroll
      for (int k = 0; k < 4; ++k) v += pbuf[4 * s + k][o][r];
      xe2[2 * s + o] = v;
    }
  __syncthreads();
  {
    int s = c >> 1, fs = c & 1;
    const float4* ps = &pl[772 + s * 260];
    a0 = 0.f;
    a1 = 0.f;
#pragma unroll
    for (int j = 0; j < 128; ++j) {
      int f = fs * 128 + j;
      float xv = xls[f * 32 + (r ^ (f & 31))];
      float4 p = ps[f];
      float e = entpair(p.x, xv);
      a0 = __builtin_fmaf(e, p.y, a0);
      a1 = __builtin_fmaf(-e, p.z, a1);
    }
    if (fs == 0) {
#pragma unroll
      for (int o = 0; o < 4; ++o) {
        float4 p = ps[256 + o];
        float e = entpair(p.x, xe2[o]);
        a0 = __builtin_fmaf(e, p.y, a0);
        a1 = __builtin_fmaf(-e, p.z, a1);
      }
    }
    pbuf[c][0][r] = a0;
    pbuf[c][1][r] = a1;
  }
  __syncthreads();
  if (c < 2) {
#pragma unroll
    for (int i = 0; i < 4; ++i) {
      int s = 2 * c + (i >> 1), o = i & 1;
      float v = cstf[6 + 2 * s + o];
#pragma unroll
      for (int k = 0; k < 2; ++k) v += pbuf[2 * s + k][o][r];
      out2T[(size_t)(4 * c + i) * SP + b0 + r] = v;
    }
  }
}

// ---------------- big levels (3,4,5): COMPACTED feature list, column-major ----------
// Block 256 thr = 4 f-groups x (64 lanes x C=2 cols). Dynamic loop over the stump's
// ~nc compacted entries (nc from cnt[]); entry = {c10, ml0/8, ml1/8, fidx}; fidx is
// the absolute row in the unified xAll[312][SP] buffer (wave-uniform base -> full
// coalescing preserved). Partials combine via LDS; cst folded into group-0 init.
template <int FD, int C, bool FINAL>
__global__ __launch_bounds__(256, 8) void ndt_bigC(const float* __restrict__ xAll,
                                                   const float4* __restrict__ cprmL,
                                                   const int* __restrict__ cntL,
                                                   const float* __restrict__ cstL,
                                                   float* __restrict__ outp,
                                                   int outRowBase) {
  constexpr int COLS = 64 * C;
  __shared__ float4 pl[288];
  __shared__ float2 pb[3][COLS];
  int tid = threadIdx.x;
  int lane = tid & 63, fh = tid >> 6;
  int s = blockIdx.y;
  int nc = cntL[s];
  const float4* cp = cprmL + (size_t)s * FD;
  for (int i = tid; i < nc; i += 256) pl[i] = cp[i];
  __syncthreads();

  int colBase = blockIdx.x * COLS + C * lane;
  float a0[C], a1[C];
  float i0 = (fh == 0) ? cstL[2 * s] : 0.f;
  float i1 = (fh == 0) ? cstL[2 * s + 1] : 0.f;
#pragma unroll
  for (int c = 0; c < C; ++c) {
    a0[c] = i0;
    a1[c] = i1;
  }

  int jlo = (fh * nc) >> 2, jhi = ((fh + 1) * nc) >> 2;
#pragma unroll 4
  for (int j = jlo; j < jhi; ++j) {
    float4 p = pl[j];
    int row = __float_as_int(p.w);
    const float* xp = xAll + (size_t)row * SP + colBase;
    float xv[C];
    if (C == 2) {
      float2 g = *(const float2*)xp;
      xv[0] = g.x;
      xv[1] = g.y;
    } else {
      float4 g = *(const float4*)xp;
      xv[0] = g.x; xv[1] = g.y; xv[2] = g.z; xv[3] = g.w;
    }
#pragma unroll
    for (int c = 0; c < C; ++c) {
      float e = entpair(p.x, xv[c]);
      a0[c] = __builtin_fmaf(e, p.y, a0[c]);
      a1[c] = __builtin_fmaf(-e, p.z, a1[c]);
    }
  }
  if (fh > 0) {
#pragma unroll
    for (int c = 0; c < C; ++c)
      pb[fh - 1][C * lane + c] = make_float2(a0[c], a1[c]);
  }
  __syncthreads();
  if (fh == 0) {
#pragma unroll
    for (int c = 0; c < C; ++c) {
#pragma unroll
      for (int g = 0; g < 3; ++g) {
        float2 t = pb[g][C * lane + c];
        a0[c] += t.x;
        a1[c] += t.y;
      }
    }
    if (FINAL) {
#pragma unroll
      for (int c = 0; c < C; ++c)
        *(float2*)(outp + (size_t)(colBase + c) * 64 + 2 * s) =
            make_float2(a0[c], a1[c]);
    } else {
      float* o0 = outp + (size_t)(outRowBase + 2 * s) * SP + colBase;
      float* o1 = o0 + SP;
      *(float2*)o0 = make_float2(a0[0], a0[1]);
      *(float2*)o1 = make_float2(a1[0], a1[1]);
    }
  }
}

extern "C" void kernel_launch(void* const* d_in, const int* in_sizes, int n_in,
                              void* d_out, int out_size, void* d_ws, size_t ws_size,
                              hipStream_t stream) {
  const float* x = (const float*)d_in[0];
  float* out = (float*)d_out;
  float* wsf = (float*)d_ws;

  // ws layout (float offsets)
  float* xAll = wsf + 0;                    // [312][SP]: 0-255 x, 256+ level outs
  float4* prm = (float4*)(wsf + 2575872);   // 17492 float4 (full)
  float4* cprm = (float4*)(wsf + 2645840);  // 17492 float4 (compacted)
  float* cstf = wsf + 2715808;              // 126 floats
  int* cnt = (int*)(wsf + 2715934);         // 63 ints

  hipLaunchKernelGGL(ndt_transpose, dim3(8, B_SZ / 32), dim3(32, 8), 0, stream,
                     x, xAll);

  MaskArgs ma;
  for (int d = 0; d < 6; ++d) {
    ma.fm[d] = (const float*)d_in[1 + 3 * d];
    ma.cp[d] = (const float*)d_in[2 + 3 * d];
    ma.lr[d] = (const float*)d_in[3 + 3 * d];
  }
  ma.out_masks = out;
  ma.prm = prm;
  ma.cprm = cprm;
  ma.cnt = cnt;
  ma.cstf = cstf;
  hipLaunchKernelGGL(ndt_masks, dim3(63), dim3(64), 0, stream, ma);

  // levels 0-2 fused; writes out2T into xAll rows 256..263
  hipLaunchKernelGGL(ndt_l012, dim3(B_SZ / 32), dim3(256), 0, stream,
                     x, prm, cstf, xAll + (size_t)256 * SP);
  // level 3: 8 stumps, compacted; out rows 264..279
  hipLaunchKernelGGL((ndt_bigC<264, 2, false>), dim3(64, 8), dim3(256), 0, stream,
                     xAll, cprm + 1812, cnt + 7, cstf + 14, wsf, 264);
  // level 4: 16 stumps; out rows 280..311
  hipLaunchKernelGGL((ndt_bigC<272, 2, false>), dim3(64, 16), dim3(256), 0, stream,
                     xAll, cprm + 3924, cnt + 15, cstf + 30, wsf, 280);
  // level 5: 32 stumps; final row-major write
  hipLaunchKernelGGL((ndt_bigC<288, 2, true>), dim3(64, 32), dim3(256), 0, stream,
                     xAll, cprm + 8276, cnt + 31, cstf + 62, out, 0);
}

// Round 15
// 51.978 us; speedup vs baseline: 1.6349x; 1.0749x over previous
//
#include <hip/hip_runtime.h>

#define B_SZ 8192
#define SP 8256  // padded row stride (floats)

// ---------------- masks + COMPACTED fused params ----------
// For d<3: compacted BASE features (fidx = f < 256) + dense extras appended at the
// end of each stump's list (p.w = extra index o). For d>=3: all active features
// compacted with absolute xAll row in p.w. cnt[stump] = compacted base count.
struct MaskArgs {
  const float* fm[6];
  const float* cp[6];
  const float* lr[6];
  float* out_masks;  // d_out base
  float4* cprm;      // compacted params {c10, ml0/8, ml1/8, fidx}
  int* cnt;          // compacted count per stump (global stump idx)
  float* cstf;       // per-output 0.5*sum(ml)
};

__device__ __forceinline__ float wave_max(float v) {
#pragma unroll
  for (int o = 32; o > 0; o >>= 1) v = fmaxf(v, __shfl_xor(v, o));
  return v;
}
__device__ __forceinline__ float wave_sum(float v) {
#pragma unroll
  for (int o = 32; o > 0; o >>= 1) v += __shfl_xor(v, o);
  return v;
}

__global__ __launch_bounds__(64) void ndt_masks(MaskArgs a) {
  const int maskOff[6] = {524288, 524544, 525060, 526100, 528212, 532564};
  const int prmOff[6]  = {0, 256, 772, 1812, 3924, 8276};
  const int cstOff[6]  = {0, 1, 3, 7, 15, 31};
  const int exBase[6]  = {0, 0, 0, 256, 264, 280};  // xAll row of extra feature 0
  int bid = blockIdx.x, lane = threadIdx.x;
  int d = 0, s = bid, n = 1;
  while (s >= n) { s -= n; n <<= 1; ++d; }   // level d, stump s, n = 2^d
  int Fd = 256 + ((d > 0) ? n : 0);

  const float* fm = a.fm[d] + (size_t)s * Fd;
  float y[5];
#pragma unroll
  for (int j = 0; j < 5; ++j) {
    int f = lane + 64 * j;
    y[j] = (f < Fd) ? fm[f] * 0.5f : -3.0e38f;
  }
  float m = fmaxf(fmaxf(fmaxf(y[0], y[1]), fmaxf(y[2], y[3])), y[4]);
  m = wave_max(m);
#pragma unroll
  for (int j = 0; j < 5; ++j) y[j] -= m;

  float lo = -1.f, hi = 0.f;
  for (int it = 0; it < 24; ++it) {
    float tau = 0.5f * (lo + hi);
    float ss = 0.f;
#pragma unroll
    for (int j = 0; j < 5; ++j) {
      float v = fmaxf(y[j] - tau, 0.f);
      ss = __builtin_fmaf(v, v, ss);
    }
    ss = wave_sum(ss);
    if (ss >= 1.f) lo = tau; else hi = tau;
  }
  float tau = 0.5f * (lo + hi);

  float* mo = a.out_masks + maskOff[d] + (size_t)s * Fd;
  const float* cp = a.cp[d] + (size_t)s * Fd * 2;
  const float* lr = a.lr[d] + (size_t)s * Fd * 2;
  float4* cpr = a.cprm + prmOff[d] + (size_t)s * Fd;
  int exB = exBase[d];
  float sum0 = 0.f, sum1 = 0.f;
  int base = 0;
  float c10x = 0.f, ml0x = 0.f, ml1x = 0.f;  // j=4 (extra-feature) values for d<3
#pragma unroll
  for (int j = 0; j < 5; ++j) {
    int f = lane + 64 * j;
    bool in = (f < Fd);
    float v = fmaxf(y[j] - tau, 0.f);
    float mk = v * v;
    float c10 = 0.f, ml0 = 0.f, ml1 = 0.f;
    if (in) {
      mo[f] = mk;
      float c0 = cp[2 * f], c1 = cp[2 * f + 1];
      ml0 = lr[2 * f] * mk;
      ml1 = lr[2 * f + 1] * mk;
      c10 = c1 - c0;
      sum0 += ml0;
      sum1 += ml1;
    }
    if (j == 4) { c10x = c10; ml0x = ml0; ml1x = ml1; }
    bool act = in && (v > 0.f) && (d >= 3 || j < 4);
    unsigned long long bm = __ballot(act);
    int pre = __popcll(bm & ((1ull << lane) - 1ull));
    if (act) {
      int fidx = (f < 256) ? f : (exB + f - 256);
      cpr[base + pre] =
          make_float4(c10, ml0 * 0.125f, ml1 * 0.125f, __int_as_float(fidx));
    }
    base += __popcll(bm);
  }
  // d<3: append dense extras (L1: 2, L2: 4) after the compacted base list
  if (d > 0 && d < 3 && lane < Fd - 256) {
    cpr[base + lane] =
        make_float4(c10x, ml0x * 0.125f, ml1x * 0.125f, __int_as_float(lane));
  }
  sum0 = wave_sum(sum0);
  sum1 = wave_sum(sum1);
  if (lane == 0) {
    a.cstf[2 * (cstOff[d] + s)] = 0.5f * sum0;
    a.cstf[2 * (cstOff[d] + s) + 1] = 0.5f * sum1;
    a.cnt[cstOff[d] + s] = base;
  }
}

// 2-elem entmax15 closed form (scaled): t = c10 - x; tc = clamp(t,-2,2);
// e' = tc*sqrt(8 - tc^2) = 8*e. The 1/8 is folded into ml at build time.
__device__ __forceinline__ float entpair(float c10, float xv) {
  float t = c10 - xv;
  float tc = __builtin_amdgcn_fmed3f(t, -2.f, 2.f);
  float u = __builtin_fmaf(tc, -tc, 8.0f);
  return tc * __builtin_amdgcn_sqrtf(u);
}

// ---------------- levels 0-2 fused (COMPACTED) + fused x transpose ----------------
// 32-row blocks, 8 groups x 32 lanes. Stages x[32][256] in LDS (bank-swizzled),
// writes the transposed tile to xAll rows 0..255 (replaces the transpose kernel),
// then runs L0/L1/L2 over compacted feature lists; out2 -> xAll rows 256..263.
__global__ __launch_bounds__(256) void ndt_l012(const float* __restrict__ x,
                                                const float4* __restrict__ cprm,
                                                const int* __restrict__ cnt,
                                                const float* __restrict__ cstf,
                                                float* __restrict__ xAll) {
  __shared__ float xls[256 * 32];
  __shared__ float4 pl[1812];
  __shared__ float pbuf[8][2][32];
  int tid = threadIdx.x;
  int r = tid & 31, c = tid >> 5;
  int b0 = blockIdx.x * 32;
  for (int i = tid; i < 1812; i += 256) pl[i] = cprm[i];
  {
    const float4* xp = (const float4*)(x + (size_t)(b0 + r) * 256 + c * 32);
#pragma unroll
    for (int j = 0; j < 8; ++j) {
      float4 g = xp[j];
      int f = c * 32 + 4 * j;
      xls[(f + 0) * 32 + (r ^ ((4 * j + 0) & 31))] = g.x;
      xls[(f + 1) * 32 + (r ^ ((4 * j + 1) & 31))] = g.y;
      xls[(f + 2) * 32 + (r ^ ((4 * j + 2) & 31))] = g.z;
      xls[(f + 3) * 32 + (r ^ ((4 * j + 3) & 31))] = g.w;
    }
  }
  __syncthreads();
  // ---- fused transpose: write x tile to xAll rows 0..255 (coalesced over r)
#pragma unroll 8
  for (int j = 0; j < 32; ++j) {
    int f = c * 32 + j;
    xAll[(size_t)f * SP + b0 + r] = xls[f * 32 + (r ^ (f & 31))];
  }
  // ---- L0: compacted list cnt[0], 8-way group split
  float a0 = 0.f, a1 = 0.f;
  {
    int nc = cnt[0];
    int jlo = (c * nc) >> 3, jhi = ((c + 1) * nc) >> 3;
#pragma unroll 4
    for (int j = jlo; j < jhi; ++j) {
      float4 p = pl[j];
      int f = __float_as_int(p.w);
      float xv = xls[f * 32 + (r ^ (f & 31))];
      float e = entpair(p.x, xv);
      a0 = __builtin_fmaf(e, p.y, a0);
      a1 = __builtin_fmaf(-e, p.z, a1);
    }
  }
  pbuf[c][0][r] = a0;
  pbuf[c][1][r] = a1;
  __syncthreads();
  float xe1[2];
#pragma unroll
  for (int o = 0; o < 2; ++o) {
    float v = cstf[o];
#pragma unroll
    for (int k = 0; k < 8; ++k) v += pbuf[k][o][r];
    xe1[o] = v;
  }
  __syncthreads();
  // ---- L1: stump c>>2, 4-way split of compacted list; extras on slice 0
  {
    int s = c >> 2, fs = c & 3;
    const float4* ps = &pl[256 + s * 258];
    int nc = cnt[1 + s];
    a0 = 0.f;
    a1 = 0.f;
    int jlo = (fs * nc) >> 2, jhi = ((fs + 1) * nc) >> 2;
#pragma unroll 4
    for (int j = jlo; j < jhi; ++j) {
      float4 p = ps[j];
      int f = __float_as_int(p.w);
      float xv = xls[f * 32 + (r ^ (f & 31))];
      float e = entpair(p.x, xv);
      a0 = __builtin_fmaf(e, p.y, a0);
      a1 = __builtin_fmaf(-e, p.z, a1);
    }
    if (fs == 0) {
#pragma unroll
      for (int o = 0; o < 2; ++o) {
        float4 p = ps[nc + o];
        float e = entpair(p.x, xe1[o]);
        a0 = __builtin_fmaf(e, p.y, a0);
        a1 = __builtin_fmaf(-e, p.z, a1);
      }
    }
    pbuf[c][0][r] = a0;
    pbuf[c][1][r] = a1;
  }
  __syncthreads();
  float xe2[4];
#pragma unroll
  for (int s = 0; s < 2; ++s)
#pragma unroll
    for (int o = 0; o < 2; ++o) {
      float v = cstf[2 + 2 * s + o];
#pragma unroll
      for (int k = 0; k < 4; ++k) v += pbuf[4 * s + k][o][r];
      xe2[2 * s + o] = v;
    }
  __syncthreads();
  // ---- L2: stump c>>1, 2-way split of compacted list; extras on slice 0
  {
    int s = c >> 1, fs = c & 1;
    const float4* ps = &pl[772 + s * 260];
    int nc = cnt[3 + s];
    a0 = 0.f;
    a1 = 0.f;
    int jlo = (fs * nc) >> 1, jhi = ((fs + 1) * nc) >> 1;
#pragma unroll 4
    for (int j = jlo; j < jhi; ++j) {
      float4 p = ps[j];
      int f = __float_as_int(p.w);
      float xv = xls[f * 32 + (r ^ (f & 31))];
      float e = entpair(p.x, xv);
      a0 = __builtin_fmaf(e, p.y, a0);
      a1 = __builtin_fmaf(-e, p.z, a1);
    }
    if (fs == 0) {
#pragma unroll
      for (int o = 0; o < 4; ++o) {
        float4 p = ps[nc + o];
        float e = entpair(p.x, xe2[o]);
        a0 = __builtin_fmaf(e, p.y, a0);
        a1 = __builtin_fmaf(-e, p.z, a1);
      }
    }
    pbuf[c][0][r] = a0;
    pbuf[c][1][r] = a1;
  }
  __syncthreads();
  // ---- reduce L2 -> xAll rows 256..263 (out2 transposed)
  if (c < 2) {
#pragma unroll
    for (int i = 0; i < 4; ++i) {
      int s = 2 * c + (i >> 1), o = i & 1;
      float v = cstf[6 + 2 * s + o];
#pragma unroll
      for (int k = 0; k < 2; ++k) v += pbuf[2 * s + k][o][r];
      xAll[(size_t)(256 + 4 * c + i) * SP + b0 + r] = v;
    }
  }
}

// ---------------- big levels (3,4,5): COMPACTED feature list, column-major ----------
// Block 256 thr = 4 f-groups x (64 lanes x C cols). Dynamic loop over the stump's
// nc compacted entries; entry = {c10, ml0/8, ml1/8, fidx}; fidx = absolute row in
// the unified xAll[312][SP] buffer (wave-uniform base -> full coalescing).
template <int FD, int C, bool FINAL>
__global__ __launch_bounds__(256, 8) void ndt_bigC(const float* __restrict__ xAll,
                                                   const float4* __restrict__ cprmL,
                                                   const int* __restrict__ cntL,
                                                   const float* __restrict__ cstL,
                                                   float* __restrict__ outp,
                                                   int outRowBase) {
  constexpr int COLS = 64 * C;
  __shared__ float4 pl[288];
  __shared__ float2 pb[3][COLS];
  int tid = threadIdx.x;
  int lane = tid & 63, fh = tid >> 6;
  int s = blockIdx.y;
  int nc = cntL[s];
  const float4* cp = cprmL + (size_t)s * FD;
  for (int i = tid; i < nc; i += 256) pl[i] = cp[i];
  __syncthreads();

  int colBase = blockIdx.x * COLS + C * lane;
  float a0[C], a1[C];
  float i0 = (fh == 0) ? cstL[2 * s] : 0.f;
  float i1 = (fh == 0) ? cstL[2 * s + 1] : 0.f;
#pragma unroll
  for (int c = 0; c < C; ++c) {
    a0[c] = i0;
    a1[c] = i1;
  }

  int jlo = (fh * nc) >> 2, jhi = ((fh + 1) * nc) >> 2;
#pragma unroll 4
  for (int j = jlo; j < jhi; ++j) {
    float4 p = pl[j];
    int row = __float_as_int(p.w);
    const float* xp = xAll + (size_t)row * SP + colBase;
    float xv[C];
    if (C == 2) {
      float2 g = *(const float2*)xp;
      xv[0] = g.x;
      xv[1] = g.y;
    } else {
      float4 g = *(const float4*)xp;
      xv[0] = g.x; xv[1] = g.y; xv[2] = g.z; xv[3] = g.w;
    }
#pragma unroll
    for (int c = 0; c < C; ++c) {
      float e = entpair(p.x, xv[c]);
      a0[c] = __builtin_fmaf(e, p.y, a0[c]);
      a1[c] = __builtin_fmaf(-e, p.z, a1[c]);
    }
  }
  if (fh > 0) {
#pragma unroll
    for (int c = 0; c < C; ++c)
      pb[fh - 1][C * lane + c] = make_float2(a0[c], a1[c]);
  }
  __syncthreads();
  if (fh == 0) {
#pragma unroll
    for (int c = 0; c < C; ++c) {
#pragma unroll
      for (int g = 0; g < 3; ++g) {
        float2 t = pb[g][C * lane + c];
        a0[c] += t.x;
        a1[c] += t.y;
      }
    }
    if (FINAL) {
#pragma unroll
      for (int c = 0; c < C; ++c)
        *(float2*)(outp + (size_t)(colBase + c) * 64 + 2 * s) =
            make_float2(a0[c], a1[c]);
    } else {
      float* o0 = outp + (size_t)(outRowBase + 2 * s) * SP + colBase;
      float* o1 = o0 + SP;
      if (C == 2) {
        *(float2*)o0 = make_float2(a0[0], a0[1]);
        *(float2*)o1 = make_float2(a1[0], a1[1]);
      } else {
        *(float4*)o0 = make_float4(a0[0], a0[1], a0[2], a0[3]);
        *(float4*)o1 = make_float4(a1[0], a1[1], a1[2], a1[3]);
      }
    }
  }
}

extern "C" void kernel_launch(void* const* d_in, const int* in_sizes, int n_in,
                              void* d_out, int out_size, void* d_ws, size_t ws_size,
                              hipStream_t stream) {
  const float* x = (const float*)d_in[0];
  float* out = (float*)d_out;
  float* wsf = (float*)d_ws;

  // ws layout (float offsets)
  float* xAll = wsf + 0;                    // [312][SP]: 0-255 x, 256+ level outs
  float4* cprm = (float4*)(wsf + 2575872);  // 17492 float4 (compacted)
  float* cstf = wsf + 2645840;              // 126 floats
  int* cnt = (int*)(wsf + 2645966);         // 63 ints

  MaskArgs ma;
  for (int d = 0; d < 6; ++d) {
    ma.fm[d] = (const float*)d_in[1 + 3 * d];
    ma.cp[d] = (const float*)d_in[2 + 3 * d];
    ma.lr[d] = (const float*)d_in[3 + 3 * d];
  }
  ma.out_masks = out;
  ma.cprm = cprm;
  ma.cnt = cnt;
  ma.cstf = cstf;
  hipLaunchKernelGGL(ndt_masks, dim3(63), dim3(64), 0, stream, ma);

  // levels 0-2 fused + x transpose; writes xAll rows 0..255 (xT) and 256..263 (out2)
  hipLaunchKernelGGL(ndt_l012, dim3(B_SZ / 32), dim3(256), 0, stream,
                     x, cprm, cnt, cstf, xAll);
  // level 3: 8 stumps, C=2; grid (64, 8) = 512 blocks; out rows 264..279
  hipLaunchKernelGGL((ndt_bigC<264, 2, false>), dim3(64, 8), dim3(256), 0, stream,
                     xAll, cprm + 1812, cnt + 7, cstf + 14, wsf, 264);
  // level 4: 16 stumps, C=4; grid (32, 16) = 512 blocks; out rows 280..311
  hipLaunchKernelGGL((ndt_bigC<272, 4, false>), dim3(32, 16), dim3(256), 0, stream,
                     xAll, cprm + 3924, cnt + 15, cstf + 30, wsf, 280);
  // level 5: 32 stumps, C=4; grid (32, 32) = 1024 blocks; final row-major write
  hipLaunchKernelGGL((ndt_bigC<288, 4, true>), dim3(32, 32), dim3(256), 0, stream,
                     xAll, cprm + 8276, cnt + 31, cstf + 62, out, 0);
}